// Round 5
// baseline (25.837 us; speedup 1.0000x reference)
//
#include <hip/hip_runtime.h>

// MedianPool: x (32, 4096, 128) f32, window=5, circular pad along dim 1,
// lower median (sorted[2] of 5). Output f32 same shape.
//
// R4: RPT=16 (20 row loads -> 16 medians, 1.25x load amplification),
// 7-op median-of-5 via v_med3_f32, XCD-contiguous block swizzle,
// nontemporal f32x4 stores.

constexpr int B   = 32;
constexpr int L   = 4096;    // power of two -> wrap via mask
constexpr int C   = 128;
constexpr int C4  = C / 4;   // f32x4 per row = 32
constexpr int RPT = 16;      // output rows per thread
constexpr int LG  = L / RPT; // 256 row-groups per batch
constexpr int NXCD = 8;

typedef float f32x4 __attribute__((ext_vector_type(4)));

__device__ __forceinline__ f32x4 f4min(f32x4 a, f32x4 b) {
    f32x4 r;
    r.x = fminf(a.x, b.x); r.y = fminf(a.y, b.y);
    r.z = fminf(a.z, b.z); r.w = fminf(a.w, b.w);
    return r;
}
__device__ __forceinline__ f32x4 f4max(f32x4 a, f32x4 b) {
    f32x4 r;
    r.x = fmaxf(a.x, b.x); r.y = fmaxf(a.y, b.y);
    r.z = fmaxf(a.z, b.z); r.w = fmaxf(a.w, b.w);
    return r;
}
__device__ __forceinline__ f32x4 f4med3(f32x4 a, f32x4 b, f32x4 c) {
    f32x4 r;
    r.x = __builtin_amdgcn_fmed3f(a.x, b.x, c.x);
    r.y = __builtin_amdgcn_fmed3f(a.y, b.y, c.y);
    r.z = __builtin_amdgcn_fmed3f(a.z, b.z, c.z);
    r.w = __builtin_amdgcn_fmed3f(a.w, b.w, c.w);
    return r;
}

// Lower median of 5, 7 ops: min of pair-minima has rank<=2, max of
// pair-maxima has rank>=4 -> discard; med3 of survivors is the answer.
__device__ __forceinline__ f32x4 median5(f32x4 a, f32x4 b, f32x4 c,
                                         f32x4 d, f32x4 e) {
    f32x4 t1 = f4min(a, b), t2 = f4max(a, b);
    f32x4 t3 = f4min(c, d), t4 = f4max(c, d);
    f32x4 t5 = f4max(t1, t3);
    f32x4 t6 = f4min(t2, t4);
    return f4med3(t5, t6, e);
}

__global__ __launch_bounds__(256)
void MedianPool_73426760893099_kernel(const f32x4* __restrict__ x,
                                      f32x4* __restrict__ out) {
    // XCD-contiguous swizzle: nwg = 1024, divisible by 8. HW round-robins
    // blockIdx across XCDs; remap so each XCD owns a contiguous chunk
    // (window-overlap rows then share that XCD's L2).
    const int nwg  = gridDim.x;
    const int cpx  = nwg / NXCD;
    const int bid  = (int)blockIdx.x;
    const int bsw  = (bid % NXCD) * cpx + bid / NXCD;

    const int idx = bsw * blockDim.x + threadIdx.x;  // over B*LG*C4 = 262,144
    const int c4 = idx & (C4 - 1);
    const int lg = (idx >> 5) & (LG - 1);
    const int b  = idx >> 13;   // idx / (LG*C4)

    const f32x4* __restrict__ xb = x + (size_t)b * L * C4;
    const int l0 = lg * RPT;

    // Load RPT + 4 = 20 rows (circular).
    f32x4 r[RPT + 4];
#pragma unroll
    for (int i = 0; i < RPT + 4; ++i)
        r[i] = xb[(size_t)((l0 + i) & (L - 1)) * C4 + c4];

    f32x4* o = out + (size_t)b * L * C4 + (size_t)l0 * C4 + c4;
#pragma unroll
    for (int i = 0; i < RPT; ++i) {
        f32x4 m = median5(r[i], r[i + 1], r[i + 2], r[i + 3], r[i + 4]);
        __builtin_nontemporal_store(m, o + i * C4);
    }
}

extern "C" void kernel_launch(void* const* d_in, const int* in_sizes, int n_in,
                              void* d_out, int out_size, void* d_ws, size_t ws_size,
                              hipStream_t stream) {
    const f32x4* x   = (const f32x4*)d_in[0];
    f32x4*       out = (f32x4*)d_out;

    const int threads = B * LG * C4;          // 262,144
    const int block   = 256;
    const int grid    = threads / block;      // 1024
    MedianPool_73426760893099_kernel<<<grid, block, 0, stream>>>(x, out);
}

// Round 6
// 24.083 us; speedup vs baseline: 1.0728x; 1.0728x over previous
//
#include <hip/hip_runtime.h>

// MedianPool: x (32, 4096, 128) f32, window=5, circular pad along dim 1,
// lower median (sorted[2] of 5). Output f32 same shape.
//
// R5: RPT=8 rolling-window (preload 6 rows, 1 load per output row after),
// __launch_bounds__(256,8) to stay in the <=64-VGPR / 8-waves-per-SIMD class,
// 7-op median-of-5 via v_med3_f32, XCD-contiguous swizzle, nontemporal stores.

constexpr int B   = 32;
constexpr int L   = 4096;    // power of two -> wrap via mask
constexpr int C   = 128;
constexpr int C4  = C / 4;   // f32x4 per row = 32
constexpr int RPT = 8;       // output rows per thread
constexpr int LG  = L / RPT; // 512 row-groups per batch
constexpr int NXCD = 8;

typedef float f32x4 __attribute__((ext_vector_type(4)));

__device__ __forceinline__ f32x4 f4min(f32x4 a, f32x4 b) {
    f32x4 r;
    r.x = fminf(a.x, b.x); r.y = fminf(a.y, b.y);
    r.z = fminf(a.z, b.z); r.w = fminf(a.w, b.w);
    return r;
}
__device__ __forceinline__ f32x4 f4max(f32x4 a, f32x4 b) {
    f32x4 r;
    r.x = fmaxf(a.x, b.x); r.y = fmaxf(a.y, b.y);
    r.z = fmaxf(a.z, b.z); r.w = fmaxf(a.w, b.w);
    return r;
}
__device__ __forceinline__ f32x4 f4med3(f32x4 a, f32x4 b, f32x4 c) {
    f32x4 r;
    r.x = __builtin_amdgcn_fmed3f(a.x, b.x, c.x);
    r.y = __builtin_amdgcn_fmed3f(a.y, b.y, c.y);
    r.z = __builtin_amdgcn_fmed3f(a.z, b.z, c.z);
    r.w = __builtin_amdgcn_fmed3f(a.w, b.w, c.w);
    return r;
}

// Lower median of 5, 7 ops: min of pair-minima has rank<=2, max of
// pair-maxima has rank>=4 -> discard; med3 of survivors is the answer.
__device__ __forceinline__ f32x4 median5(f32x4 a, f32x4 b, f32x4 c,
                                         f32x4 d, f32x4 e) {
    f32x4 t1 = f4min(a, b), t2 = f4max(a, b);
    f32x4 t3 = f4min(c, d), t4 = f4max(c, d);
    f32x4 t5 = f4max(t1, t3);
    f32x4 t6 = f4min(t2, t4);
    return f4med3(t5, t6, e);
}

__global__ __launch_bounds__(256, 8)
void MedianPool_73426760893099_kernel(const f32x4* __restrict__ x,
                                      f32x4* __restrict__ out) {
    // XCD-contiguous swizzle: nwg = 2048, divisible by 8.
    const int nwg  = gridDim.x;
    const int cpx  = nwg / NXCD;
    const int bid  = (int)blockIdx.x;
    const int bsw  = (bid % NXCD) * cpx + bid / NXCD;

    const int idx = bsw * blockDim.x + threadIdx.x;  // over B*LG*C4 = 524,288
    const int c4 = idx & (C4 - 1);
    const int lg = (idx >> 5) & (LG - 1);
    const int b  = idx >> 14;   // idx / (LG*C4)

    const f32x4* __restrict__ xb = x + (size_t)b * L * C4;
    const int l0 = lg * RPT;

    // Rolling window: keep <=7 rows live. r[] with static indices only.
    f32x4 r[RPT + 4];
    // Preload 6 rows.
#pragma unroll
    for (int i = 0; i < 6; ++i)
        r[i] = xb[(size_t)((l0 + i) & (L - 1)) * C4 + c4];

    f32x4* o = out + (size_t)b * L * C4 + (size_t)l0 * C4 + c4;
#pragma unroll
    for (int i = 0; i < RPT; ++i) {
        // Load one row ahead (row i+6) before computing output i, so the
        // load is in flight while we do the min/max network.
        if (i + 6 < RPT + 4)
            r[i + 6] = xb[(size_t)((l0 + i + 6) & (L - 1)) * C4 + c4];
        f32x4 m = median5(r[i], r[i + 1], r[i + 2], r[i + 3], r[i + 4]);
        __builtin_nontemporal_store(m, o + i * C4);
    }
}

extern "C" void kernel_launch(void* const* d_in, const int* in_sizes, int n_in,
                              void* d_out, int out_size, void* d_ws, size_t ws_size,
                              hipStream_t stream) {
    const f32x4* x   = (const f32x4*)d_in[0];
    f32x4*       out = (f32x4*)d_out;

    const int threads = B * LG * C4;          // 524,288
    const int block   = 256;
    const int grid    = threads / block;      // 2048
    MedianPool_73426760893099_kernel<<<grid, block, 0, stream>>>(x, out);
}